// Round 1
// baseline (1252.249 us; speedup 1.0000x reference)
//
#include <hip/hip_runtime.h>
#include <math.h>

// ---------------------------------------------------------------------------
// GraphSAGE 3-layer + classifier + log_softmax, fused per-layer kernels.
// Strategy: build CSR (by dst) once per call, then wave-per-node fused
// aggregate+linear kernels.  All f32 math (threshold is bf16-level, f32 is
// far inside it).
// ---------------------------------------------------------------------------

__global__ void deg_kernel(const int* __restrict__ dst, int* __restrict__ deg, int E) {
    int i = blockIdx.x * blockDim.x + threadIdx.x;
    int stride = gridDim.x * blockDim.x;
    for (; i < E; i += stride) atomicAdd(&deg[dst[i]], 1);
}

// Single-block exclusive scan of deg[n] -> rowptr[n+1].  n=100000: each of
// 1024 threads serially scans a ~98-element chunk, Hillis-Steele over chunk
// sums in LDS, then writes its chunk's exclusive prefixes.
__global__ __launch_bounds__(1024) void scan_kernel(const int* __restrict__ deg,
                                                    int* __restrict__ rowptr, int n) {
    __shared__ int sums[1024];
    int t = threadIdx.x;
    int chunk = (n + 1023) >> 10;
    int begin = t * chunk; if (begin > n) begin = n;
    int end = begin + chunk; if (end > n) end = n;
    int s = 0;
    for (int i = begin; i < end; ++i) s += deg[i];
    sums[t] = s;
    __syncthreads();
    for (int off = 1; off < 1024; off <<= 1) {
        int v = (t >= off) ? sums[t - off] : 0;
        __syncthreads();
        sums[t] += v;
        __syncthreads();
    }
    int run = (t == 0) ? 0 : sums[t - 1];
    for (int i = begin; i < end; ++i) { rowptr[i] = run; run += deg[i]; }
    if (t == 1023) rowptr[n] = sums[1023];
}

__global__ void fill_kernel(const int* __restrict__ src, const int* __restrict__ dst,
                            const int* __restrict__ rowptr, int* __restrict__ cursor,
                            int* __restrict__ col, int E) {
    int i = blockIdx.x * blockDim.x + threadIdx.x;
    int stride = gridDim.x * blockDim.x;
    for (; i < E; i += stride) {
        int d = dst[i];
        int p = atomicAdd(&cursor[d], 1);
        col[rowptr[d] + p] = src[i];
    }
}

// Fused SAGE layer: out[v] = relu( mean_{s in N(v)} xin[s] @ Wl + bl + xin[v] @ Wr )
// One wave per node, lane = feature.  Wl/Wr interleaved as float2 in LDS so the
// 64-step matmul is 1x ds_read_b64 (broadcast row) + 1x ds_read_b64 (weights)
// + 2 fma per k.
__global__ __launch_bounds__(256) void sage_layer(
    const float* __restrict__ xin, float* __restrict__ xout,
    const int* __restrict__ rowptr, const int* __restrict__ col,
    const float* __restrict__ Wl, const float* __restrict__ bl,
    const float* __restrict__ Wr, int n, int relu)
{
    __shared__ float2 w2[64 * 64];      // {Wl[k][f], Wr[k][f]}
    __shared__ float sbl[64];
    __shared__ float2 rows[4][64];      // per-wave {mean, xv} row
    int tid = threadIdx.x;
    for (int i = tid; i < 64 * 64; i += 256) w2[i] = make_float2(Wl[i], Wr[i]);
    if (tid < 64) sbl[tid] = bl[tid];
    __syncthreads();

    int wid = tid >> 6, lane = tid & 63;
    int w = blockIdx.x * 4 + wid;
    int nw = gridDim.x * 4;
    for (int v = w; v < n; v += nw) {
        int s0 = rowptr[v], s1 = rowptr[v + 1];
        float xv = xin[(size_t)v * 64 + lane];
        float acc = 0.f;
        for (int i = s0; i < s1; ++i) {
            int s = col[i];
            acc += xin[(size_t)s * 64 + lane];   // coalesced 256B row read
        }
        float mean = acc / fmaxf((float)(s1 - s0), 1.0f);
        rows[wid][lane] = make_float2(mean, xv); // wave-local: compiler orders via lgkmcnt
        float out = sbl[lane];
        #pragma unroll
        for (int k = 0; k < 64; ++k) {
            float2 m = rows[wid][k];             // broadcast read
            float2 ww = w2[k * 64 + lane];
            out += m.x * ww.x + m.y * ww.y;
        }
        if (relu) out = fmaxf(out, 0.f);
        xout[(size_t)v * 64 + lane] = out;
    }
}

// Classifier + log_softmax.  Each wave handles 4 nodes (one per 16-lane group);
// lanes 0..9 of each group compute one class each, then width-16 shfl_xor
// reductions for max / sum-exp.
__global__ __launch_bounds__(256) void cls_kernel(
    const float* __restrict__ h, const float* __restrict__ Wc,
    const float* __restrict__ bc, float* __restrict__ out, int n)
{
    __shared__ float sW[64 * 10];
    __shared__ float sb[16];
    __shared__ float srow[4][4][64];
    int tid = threadIdx.x;
    for (int i = tid; i < 640; i += 256) sW[i] = Wc[i];
    if (tid < 10) sb[tid] = bc[tid];
    __syncthreads();

    int wid = tid >> 6, lane = tid & 63;
    int grp = lane >> 4, l16 = lane & 15;
    int w = blockIdx.x * 4 + wid;
    int nw = gridDim.x * 4;
    int ngroups = (n + 3) >> 2;
    for (int g = w; g < ngroups; g += nw) {
        int v0 = g * 4;
        #pragma unroll
        for (int r = 0; r < 4; ++r) {
            int vv = v0 + r;
            if (vv < n) srow[wid][r][lane] = h[(size_t)vv * 64 + lane];
        }
        int v = v0 + grp;
        float z = -INFINITY;
        if (v < n && l16 < 10) {
            z = sb[l16];
            #pragma unroll
            for (int k = 0; k < 64; ++k)
                z += srow[wid][grp][k] * sW[k * 10 + l16];
        }
        float m = z;
        for (int off = 8; off > 0; off >>= 1)
            m = fmaxf(m, __shfl_xor(m, off, 16));
        float e = (l16 < 10 && v < n) ? expf(z - m) : 0.f;
        float ssum = e;
        for (int off = 8; off > 0; off >>= 1)
            ssum += __shfl_xor(ssum, off, 16);
        if (v < n && l16 < 10)
            out[(size_t)v * 10 + l16] = z - m - logf(ssum);
    }
}

extern "C" void kernel_launch(void* const* d_in, const int* in_sizes, int n_in,
                              void* d_out, int out_size, void* d_ws, size_t ws_size,
                              hipStream_t stream) {
    const float* x   = (const float*)d_in[0];
    const int*   ei  = (const int*)d_in[1];     // int32 (JAX canonicalizes int64)
    const float* Wl1 = (const float*)d_in[2];
    const float* bl1 = (const float*)d_in[3];
    const float* Wr1 = (const float*)d_in[4];
    const float* Wl2 = (const float*)d_in[5];
    const float* bl2 = (const float*)d_in[6];
    const float* Wr2 = (const float*)d_in[7];
    const float* Wl3 = (const float*)d_in[8];
    const float* bl3 = (const float*)d_in[9];
    const float* Wr3 = (const float*)d_in[10];
    const float* Wc  = (const float*)d_in[11];
    const float* bc  = (const float*)d_in[12];
    float* outp = (float*)d_out;

    int n = in_sizes[0] / 64;
    int E = in_sizes[1] / 2;
    const int* srcp = ei;
    const int* dstp = ei + E;

    char* ws = (char*)d_ws;
    size_t off = 0;
    auto alloc = [&](size_t bytes) -> void* {
        void* p = ws + off;
        off += bytes;
        off = (off + 255) & ~(size_t)255;
        return p;
    };
    int*   deg    = (int*)alloc((size_t)n * 4);
    int*   rowptr = (int*)alloc((size_t)(n + 1) * 4);
    int*   cursor = (int*)alloc((size_t)n * 4);
    int*   colv   = (int*)alloc((size_t)E * 4);
    float* h1     = (float*)alloc((size_t)n * 64 * 4);
    float* h2     = (float*)alloc((size_t)n * 64 * 4);
    (void)ws_size; (void)n_in; (void)out_size;

    hipMemsetAsync(deg, 0, (size_t)n * 4, stream);
    hipMemsetAsync(cursor, 0, (size_t)n * 4, stream);

    deg_kernel<<<512, 256, 0, stream>>>(dstp, deg, E);
    scan_kernel<<<1, 1024, 0, stream>>>(deg, rowptr, n);
    fill_kernel<<<512, 256, 0, stream>>>(srcp, dstp, rowptr, cursor, colv, E);

    sage_layer<<<2048, 256, 0, stream>>>(x,  h1, rowptr, colv, Wl1, bl1, Wr1, n, 1);
    sage_layer<<<2048, 256, 0, stream>>>(h1, h2, rowptr, colv, Wl2, bl2, Wr2, n, 1);
    sage_layer<<<2048, 256, 0, stream>>>(h2, h1, rowptr, colv, Wl3, bl3, Wr3, n, 1);
    cls_kernel<<<1024, 256, 0, stream>>>(h1, Wc, bc, outp, n);
}

// Round 5
// 626.153 us; speedup vs baseline: 1.9999x; 1.9999x over previous
//
#include <hip/hip_runtime.h>
#include <math.h>

// ---------------------------------------------------------------------------
// GraphSAGE 3-layer + classifier + log_softmax.
// Round 2 (resubmit x3 after infra timeouts): latency-hiding rewrite.
//  - CSR build with coalesced hierarchical scan (3 small kernels).
//  - sage_layer: weights in VGPRs (128/lane), neighbor indices loaded
//    coalesced + shfl-broadcast, row gathers unrolled x8 for MLP.
// ---------------------------------------------------------------------------

__global__ void deg_kernel(const int* __restrict__ dst, int* __restrict__ deg, int E) {
    int i = blockIdx.x * blockDim.x + threadIdx.x;
    int stride = gridDim.x * blockDim.x;
    for (; i < E; i += stride) atomicAdd(&deg[dst[i]], 1);
}

// K1: per-block (256-elem chunk) sums of deg
__global__ __launch_bounds__(256) void blocksum_kernel(const int* __restrict__ deg,
                                                       int* __restrict__ bsum, int n) {
    int i = blockIdx.x * 256 + threadIdx.x;
    int v = (i < n) ? deg[i] : 0;
    #pragma unroll
    for (int off = 32; off > 0; off >>= 1) v += __shfl_down(v, off);
    __shared__ int ws_[4];
    if ((threadIdx.x & 63) == 0) ws_[threadIdx.x >> 6] = v;
    __syncthreads();
    if (threadIdx.x == 0) bsum[blockIdx.x] = ws_[0] + ws_[1] + ws_[2] + ws_[3];
}

// K2: single block scans block sums (nb <= 1024) -> exclusive; writes rowptr[n]
__global__ __launch_bounds__(1024) void scan_bsum_kernel(int* __restrict__ bsum, int nb,
                                                         int* __restrict__ rowptr, int n) {
    __shared__ int s[1024];
    int t = threadIdx.x;
    int v = (t < nb) ? bsum[t] : 0;
    s[t] = v;
    __syncthreads();
    for (int off = 1; off < 1024; off <<= 1) {
        int u = (t >= off) ? s[t - off] : 0;
        __syncthreads();
        s[t] += u;
        __syncthreads();
    }
    if (t < nb) bsum[t] = s[t] - v;      // exclusive prefix of block sums
    if (t == 0) rowptr[n] = s[1023];     // total edge count
}

// K3: intra-block exclusive scan + block offset -> rowptr[i]
__global__ __launch_bounds__(256) void rowptr_kernel(const int* __restrict__ deg,
                                                     const int* __restrict__ bsum,
                                                     int* __restrict__ rowptr, int n) {
    __shared__ int s[256];
    int t = threadIdx.x;
    int i = blockIdx.x * 256 + t;
    int v = (i < n) ? deg[i] : 0;
    s[t] = v;
    __syncthreads();
    for (int off = 1; off < 256; off <<= 1) {
        int u = (t >= off) ? s[t - off] : 0;
        __syncthreads();
        s[t] += u;
        __syncthreads();
    }
    if (i < n) rowptr[i] = bsum[blockIdx.x] + s[t] - v;
}

__global__ void fill_kernel(const int* __restrict__ src, const int* __restrict__ dst,
                            const int* __restrict__ rowptr, int* __restrict__ cursor,
                            int* __restrict__ col, int E) {
    int i = blockIdx.x * blockDim.x + threadIdx.x;
    int stride = gridDim.x * blockDim.x;
    for (; i < E; i += stride) {
        int d = dst[i];
        int p = atomicAdd(&cursor[d], 1);
        col[rowptr[d] + p] = src[i];
    }
}

// Fused SAGE layer: out[v] = relu( mean_{s in N(v)} xin[s] @ Wl + bl + xin[v] @ Wr )
// One wave per node, lane = output feature.  Each lane holds its weight
// COLUMNS (Wl[:,lane], Wr[:,lane]) in 128 VGPRs; LDS holds only the per-wave
// {mean, xv} broadcast row (512 B).  Neighbor gather: coalesced col[] load +
// shfl broadcast + x8-unrolled row loads for memory-level parallelism.
__global__ __launch_bounds__(256, 2) void sage_layer(
    const float* __restrict__ xin, float* __restrict__ xout,
    const int* __restrict__ rowptr, const int* __restrict__ col,
    const float* __restrict__ Wl, const float* __restrict__ bl,
    const float* __restrict__ Wr, int n, int relu)
{
    __shared__ float2 rows[4][64];
    int tid = threadIdx.x;
    int wid = tid >> 6, lane = tid & 63;

    float wl[64], wr[64];
    #pragma unroll
    for (int k = 0; k < 64; ++k) {
        wl[k] = Wl[k * 64 + lane];   // coalesced; identical across waves -> L1/L2
        wr[k] = Wr[k * 64 + lane];
    }
    float blv = bl[lane];

    int w = blockIdx.x * 4 + wid;
    int nw = gridDim.x * 4;
    for (int v = w; v < n; v += nw) {
        int s0 = rowptr[v], s1 = rowptr[v + 1];
        int deg = s1 - s0;
        float xv = xin[(size_t)v * 64 + lane];
        float acc = 0.f;
        for (int base = 0; base < deg; base += 64) {
            int rem = deg - base;
            int cnt = rem < 64 ? rem : 64;
            int ci = (lane < cnt) ? col[s0 + base + lane] : 0;
            int j = 0;
            for (; j + 8 <= cnt; j += 8) {
                int i0 = __shfl(ci, j + 0), i1 = __shfl(ci, j + 1);
                int i2 = __shfl(ci, j + 2), i3 = __shfl(ci, j + 3);
                int i4 = __shfl(ci, j + 4), i5 = __shfl(ci, j + 5);
                int i6 = __shfl(ci, j + 6), i7 = __shfl(ci, j + 7);
                float t0 = xin[(size_t)i0 * 64 + lane];
                float t1 = xin[(size_t)i1 * 64 + lane];
                float t2 = xin[(size_t)i2 * 64 + lane];
                float t3 = xin[(size_t)i3 * 64 + lane];
                float t4 = xin[(size_t)i4 * 64 + lane];
                float t5 = xin[(size_t)i5 * 64 + lane];
                float t6 = xin[(size_t)i6 * 64 + lane];
                float t7 = xin[(size_t)i7 * 64 + lane];
                acc += ((t0 + t1) + (t2 + t3)) + ((t4 + t5) + (t6 + t7));
            }
            for (; j + 4 <= cnt; j += 4) {
                int i0 = __shfl(ci, j + 0), i1 = __shfl(ci, j + 1);
                int i2 = __shfl(ci, j + 2), i3 = __shfl(ci, j + 3);
                float t0 = xin[(size_t)i0 * 64 + lane];
                float t1 = xin[(size_t)i1 * 64 + lane];
                float t2 = xin[(size_t)i2 * 64 + lane];
                float t3 = xin[(size_t)i3 * 64 + lane];
                acc += (t0 + t1) + (t2 + t3);
            }
            for (; j < cnt; ++j)
                acc += xin[(size_t)__shfl(ci, j) * 64 + lane];
        }
        float mean = acc / fmaxf((float)deg, 1.0f);
        rows[wid][lane] = make_float2(mean, xv);   // wave-local; compiler orders
        float out = blv;
        #pragma unroll
        for (int k = 0; k < 64; ++k) {
            float2 m = rows[wid][k];               // uniform-addr broadcast read
            out = fmaf(m.x, wl[k], out);
            out = fmaf(m.y, wr[k], out);
        }
        if (relu) out = fmaxf(out, 0.f);
        xout[(size_t)v * 64 + lane] = out;
    }
}

// Classifier + log_softmax.  Wave handles 4 nodes (16-lane groups).
__global__ __launch_bounds__(256) void cls_kernel(
    const float* __restrict__ h, const float* __restrict__ Wc,
    const float* __restrict__ bc, float* __restrict__ out, int n)
{
    __shared__ float sW[64 * 10];
    __shared__ float sb[16];
    __shared__ float srow[4][4][64];
    int tid = threadIdx.x;
    for (int i = tid; i < 640; i += 256) sW[i] = Wc[i];
    if (tid < 10) sb[tid] = bc[tid];
    __syncthreads();

    int wid = tid >> 6, lane = tid & 63;
    int grp = lane >> 4, l16 = lane & 15;
    int w = blockIdx.x * 4 + wid;
    int nw = gridDim.x * 4;
    int ngroups = (n + 3) >> 2;
    for (int g = w; g < ngroups; g += nw) {
        int v0 = g * 4;
        #pragma unroll
        for (int r = 0; r < 4; ++r) {
            int vv = v0 + r;
            if (vv < n) srow[wid][r][lane] = h[(size_t)vv * 64 + lane];
        }
        int v = v0 + grp;
        float z = -INFINITY;
        if (v < n && l16 < 10) {
            z = sb[l16];
            #pragma unroll
            for (int k = 0; k < 64; ++k)
                z += srow[wid][grp][k] * sW[k * 10 + l16];
        }
        float m = z;
        for (int off = 8; off > 0; off >>= 1)
            m = fmaxf(m, __shfl_xor(m, off, 16));
        float e = (l16 < 10 && v < n) ? expf(z - m) : 0.f;
        float ssum = e;
        for (int off = 8; off > 0; off >>= 1)
            ssum += __shfl_xor(ssum, off, 16);
        if (v < n && l16 < 10)
            out[(size_t)v * 10 + l16] = z - m - logf(ssum);
    }
}

extern "C" void kernel_launch(void* const* d_in, const int* in_sizes, int n_in,
                              void* d_out, int out_size, void* d_ws, size_t ws_size,
                              hipStream_t stream) {
    const float* x   = (const float*)d_in[0];
    const int*   ei  = (const int*)d_in[1];
    const float* Wl1 = (const float*)d_in[2];
    const float* bl1 = (const float*)d_in[3];
    const float* Wr1 = (const float*)d_in[4];
    const float* Wl2 = (const float*)d_in[5];
    const float* bl2 = (const float*)d_in[6];
    const float* Wr2 = (const float*)d_in[7];
    const float* Wl3 = (const float*)d_in[8];
    const float* bl3 = (const float*)d_in[9];
    const float* Wr3 = (const float*)d_in[10];
    const float* Wc  = (const float*)d_in[11];
    const float* bc  = (const float*)d_in[12];
    float* outp = (float*)d_out;

    int n = in_sizes[0] / 64;
    int E = in_sizes[1] / 2;
    const int* srcp = ei;
    const int* dstp = ei + E;

    char* ws = (char*)d_ws;
    size_t off = 0;
    auto alloc = [&](size_t bytes) -> void* {
        void* p = ws + off;
        off += bytes;
        off = (off + 255) & ~(size_t)255;
        return p;
    };
    int nb = (n + 255) / 256;
    int*   deg    = (int*)alloc((size_t)n * 4);
    int*   rowptr = (int*)alloc((size_t)(n + 1) * 4);
    int*   cursor = (int*)alloc((size_t)n * 4);
    int*   bsum   = (int*)alloc((size_t)nb * 4);
    int*   colv   = (int*)alloc((size_t)E * 4);
    float* h1     = (float*)alloc((size_t)n * 64 * 4);
    float* h2     = (float*)alloc((size_t)n * 64 * 4);
    (void)ws_size; (void)n_in; (void)out_size;

    hipMemsetAsync(deg, 0, (size_t)n * 4, stream);
    hipMemsetAsync(cursor, 0, (size_t)n * 4, stream);

    deg_kernel<<<512, 256, 0, stream>>>(dstp, deg, E);
    blocksum_kernel<<<nb, 256, 0, stream>>>(deg, bsum, n);
    scan_bsum_kernel<<<1, 1024, 0, stream>>>(bsum, nb, rowptr, n);
    rowptr_kernel<<<nb, 256, 0, stream>>>(deg, bsum, rowptr, n);
    fill_kernel<<<512, 256, 0, stream>>>(srcp, dstp, rowptr, cursor, colv, E);

    sage_layer<<<2048, 256, 0, stream>>>(x,  h1, rowptr, colv, Wl1, bl1, Wr1, n, 1);
    sage_layer<<<2048, 256, 0, stream>>>(h1, h2, rowptr, colv, Wl2, bl2, Wr2, n, 1);
    sage_layer<<<2048, 256, 0, stream>>>(h2, h1, rowptr, colv, Wl3, bl3, Wr3, n, 1);
    cls_kernel<<<1024, 256, 0, stream>>>(h1, Wc, bc, outp, n);
}